// Round 4
// baseline (332.523 us; speedup 1.0000x reference)
//
#include <hip/hip_runtime.h>
#include <stdint.h>

#define M_DIM 8192   // 4*2048 rows of x
#define IN_F  4096
#define OUT_F 4096
#define P_LAY 4

// Factorized algorithm (W is low-rank by construction):
//   W[o,i] = sp*(vq[t*16+i8, p, :]·wdec[p,:,c]) + sp*bdec[p,c] + dmean[p]
//     with p=o>>10, t=o&1023, i8=i>>8, c=i&255, sp=dstd[p]+1e-6
//   out[s,o] = sp * Sum_j y[s,p,j]*vqh[p,t,j] + rowterm[s,p] + bias[o]
//     y[s,p,i8,l] = Sum_c x[s,i8*256+c]*wdec[p,l,c]      (stage 1, 9.7 GFLOP)
//     j = l*16 + i8 (l-major; chosen so stage-1 epilogue stores coalesce)
//     rowterm[s,p] = sp*Sum_c xc[s,c]*bdec[p,c] + dmean[p]*xsum[s]
// 43 GFLOP total vs 275 GFLOP direct; no i8 quantization needed.

typedef __attribute__((ext_vector_type(8))) short short8;   // 8 bf16 (4 VGPR)
typedef __attribute__((ext_vector_type(4))) float f32x4;

__device__ inline unsigned short f2bf(float f) {            // RNE f32->bf16
    unsigned int u = __builtin_bit_cast(unsigned int, f);
    u += 0x7fffu + ((u >> 16) & 1u);
    return (unsigned short)(u >> 16);
}

// ---------------- kernel 1: build bf16 vq table ----------------------------
// vqh[p][t][j= l*16+i8] = bf16(vq[(t*16+i8)*4*32 + p*32 + l])   (4 MB)
__global__ __launch_bounds__(256)
void prep_tables(const float* __restrict__ vq, unsigned short* __restrict__ vqh) {
    const int o4  = (blockIdx.x * 256 + threadIdx.x) * 4;  // 4 consecutive j
    const int p   = o4 >> 19;
    const int t   = (o4 >> 9) & 1023;
    const int l   = (o4 >> 4) & 31;
    const int i80 = o4 & 15;
    ushort4 pk;
    pk.x = f2bf(vq[((size_t)(t * 16 + i80 + 0) * 4 + p) * 32 + l]);
    pk.y = f2bf(vq[((size_t)(t * 16 + i80 + 1) * 4 + p) * 32 + l]);
    pk.z = f2bf(vq[((size_t)(t * 16 + i80 + 2) * 4 + p) * 32 + l]);
    pk.w = f2bf(vq[((size_t)(t * 16 + i80 + 3) * 4 + p) * 32 + l]);
    *(ushort4*)(vqh + o4) = pk;
}

// ---------------- kernel 2: stage-1 GEMM, c-split block-tiled --------------
// A = x viewed as [131072][256] (row r = s*16+i8). Per block (256 thr, 4
// waves): 8 s-rows (2 per wave), all 144 output cols, K=256 split into two
// c-halves of 128. B-table half (144 rows x 128 c, incl. bdec rows 128..131,
// ones row 132, zero rows 133..143) staged f32->bf16 into 36.9 KB LDS with
// XOR swizzle (row stride 256 B -> 16-way conflict unswizzled; ^(row&7)<<4
// makes each 16-lane quarter conflict-free). ROUND-3 BUG FIX: the XOR must
// apply to the FULL in-row offset (kc*64+kg*16) — precomputing kg*16^mask
// and ADDING kc*64 carried into bit 7 when mask bit 6 met kc's bit 6
// (fr&4, kc odd), reading the wrong slot. Write/read now share the same
// involution (rule #21). 36.9 KB LDS + LB(256,3) -> 12 waves/CU. All 16
// x-loads of a half batch-issued before the barrier for latency hiding.
__global__ __launch_bounds__(256, 3)
void gen_y(const float* __restrict__ x, const float* __restrict__ wdec,
           const float* __restrict__ bdec, const float* __restrict__ dmean,
           const float* __restrict__ dstd,
           unsigned short* __restrict__ y,       // [4][8192][512] bf16
           float* __restrict__ rowterm) {        // [8192][4] f32
    __shared__ __attribute__((aligned(16))) unsigned short sW[18432]; // 36.9 KB

    const int tid  = threadIdx.x;
    const int lane = tid & 63;
    const int wave = tid >> 6;
    const int fr   = lane & 15;
    const int kg   = lane >> 4;
    const int bswz = (fr & 7) << 4;             // per-row swizzle mask (row&7==fr&7)
    const int sb   = blockIdx.x * 8 + wave * 2; // 2 s-rows per wave

    f32x4 acc[2][9] = {};

    #pragma unroll
    for (int h = 0; h < 2; ++h) {
        if (h) __syncthreads();          // all h=0 reads done before overwrite
        // ---- stage half h of the B-table (f32 -> bf16, swizzled) ----
        #pragma unroll
        for (int it = 0; it < 18; ++it) {
            const int idx = it * 256 + tid;        // [0, 4608)
            const int n   = idx >> 5;              // row 0..143
            const int c4  = (idx & 31) * 4;        // c within half
            const int cg  = h * 128 + c4;
            float4 v;
            if (n < 128)       v = *(const float4*)(wdec + n * 256 + cg);
            else if (n < 132)  v = *(const float4*)(bdec + (n - 128) * 256 + cg);
            else if (n == 132) v = float4{1.f, 1.f, 1.f, 1.f};
            else               v = float4{0.f, 0.f, 0.f, 0.f};
            ushort4 pk;
            pk.x = f2bf(v.x); pk.y = f2bf(v.y); pk.z = f2bf(v.z); pk.w = f2bf(v.w);
            *(ushort4*)((char*)sW + n * 256 + ((c4 * 2) ^ ((n & 7) << 4))) = pk;
        }
        // ---- batch-issue all x loads for this half (fly across barrier) ----
        float4 xu[2][4], xv[2][4];
        #pragma unroll
        for (int mi = 0; mi < 2; ++mi) {
            #pragma unroll
            for (int kc = 0; kc < 4; ++kc) {
                const float* xp = x + (size_t)(sb + mi) * IN_F + fr * 256
                                + h * 128 + kc * 32 + kg * 8;
                xu[mi][kc] = *(const float4*)(xp);
                xv[mi][kc] = *(const float4*)(xp + 4);
            }
        }
        __syncthreads();
        short8 a[2][4];
        #pragma unroll
        for (int mi = 0; mi < 2; ++mi) {
            #pragma unroll
            for (int kc = 0; kc < 4; ++kc) {
                short8 t;
                t[0] = (short)f2bf(xu[mi][kc].x); t[1] = (short)f2bf(xu[mi][kc].y);
                t[2] = (short)f2bf(xu[mi][kc].z); t[3] = (short)f2bf(xu[mi][kc].w);
                t[4] = (short)f2bf(xv[mi][kc].x); t[5] = (short)f2bf(xv[mi][kc].y);
                t[6] = (short)f2bf(xv[mi][kc].z); t[7] = (short)f2bf(xv[mi][kc].w);
                a[mi][kc] = t;
            }
        }
        #pragma unroll
        for (int nt = 0; nt < 9; ++nt) {
            #pragma unroll
            for (int kc = 0; kc < 4; ++kc) {
                const short8 b = *(const short8*)((const char*)sW
                               + (nt * 16 + fr) * 256
                               + ((kc * 64 + kg * 16) ^ bswz));   // full-offset XOR
                acc[0][nt] = __builtin_amdgcn_mfma_f32_16x16x32_bf16(
                    a[0][kc], b, acc[0][nt], 0, 0, 0);
                acc[1][nt] = __builtin_amdgcn_mfma_f32_16x16x32_bf16(
                    a[1][kc], b, acc[1][nt], 0, 0, 0);
            }
        }
    }

    // y store: C/D col=lane&15, row(i8)=(lane>>4)*4+r. j = l*16+i8 with
    // l=(nt&1)*16+fr: offset = (nt&1)*256 + fr*16 + kg*4. Wave covers 512B
    // contiguous per (mi,nt) store.
    #pragma unroll
    for (int mi = 0; mi < 2; ++mi) {
        const int s = sb + mi;
        #pragma unroll
        for (int nt = 0; nt < 8; ++nt) {
            ushort4 pk;
            pk.x = f2bf(acc[mi][nt][0]); pk.y = f2bf(acc[mi][nt][1]);
            pk.z = f2bf(acc[mi][nt][2]); pk.w = f2bf(acc[mi][nt][3]);
            const size_t off = ((size_t)((nt >> 1) * M_DIM + s) * 512)
                             + (nt & 1) * 256 + fr * 16 + kg * 4;
            *(ushort4*)(y + off) = pk;
        }
        // rowterm from nt=8 frag: cols 128+fr (fr<4 -> xb[p], fr==4 -> xsum)
        float cs = acc[mi][8][0] + acc[mi][8][1] + acc[mi][8][2] + acc[mi][8][3];
        cs += __shfl_xor(cs, 16);
        cs += __shfl_xor(cs, 32);
        const float xsum = __shfl(cs, 4);
        if (lane < 4)
            rowterm[s * 4 + lane] = (dstd[lane] + 1e-6f) * cs + dmean[lane] * xsum;
    }
}

// ---------------- kernel 3: stage-2 GEMM  out = sp*(Y_p @ V_p^T) + ... -----
__device__ inline void async16(const void* g, void* l) {
    __builtin_amdgcn_global_load_lds(
        (const __attribute__((address_space(1))) void*)g,
        (__attribute__((address_space(3))) void*)l, 16, 0, 0);
}

// Same verified structure as the round-0 gemm_i8: 128x128 tile, 4 waves 2x2,
// 2-barrier K-step, global_load_lds width=16, frag diet. bf16 16x16x32, K=512.
// Frozen (attribution discipline).
__global__ __launch_bounds__(256, 4)
void gemm_y(const unsigned short* __restrict__ Y,   // [4][8192][512] bf16
            const unsigned short* __restrict__ V,   // [4][1024][512] bf16
            const float* __restrict__ rowterm,      // [8192][4]
            const float* __restrict__ dstd,
            const float* __restrict__ bias,
            float* __restrict__ C) {
    __shared__ __attribute__((aligned(16))) unsigned short sA[2 * 128 * 32]; // 16 KB
    __shared__ __attribute__((aligned(16))) unsigned short sB[2 * 128 * 32];

    const int tid  = threadIdx.x;
    const int lane = tid & 63;
    const int wave = tid >> 6;
    const int wm = (wave >> 1) * 64;
    const int wn = (wave & 1) * 64;

    const int m0 = blockIdx.x * 128;
    const int n0 = blockIdx.y * 128;
    const int p  = n0 >> 10;
    const int t0 = n0 & 1023;

    const char* gAb = (const char*)(Y + (size_t)p * M_DIM * 512);
    const char* gBb = (const char*)(V + (size_t)p * 1024  * 512);

    f32x4 acc[4][4] = {};
    for (int k0 = 0; k0 < 512; k0 += 64) {
        __syncthreads();
        #pragma unroll
        for (int q = 0; q < 4; q++) {
            const int u      = wave * 4 + q;
            const int kc     = u >> 3;
            const int rowblk = (u & 7) * 16;
            const int row    = rowblk + (lane >> 2);
            const int cb     = (lane & 3) * 16;
            const size_t gofs = (size_t)k0 * 2 + kc * 64 + cb;
            char* ldst = (char*)sA + kc * 8192 + rowblk * 64 + lane * 16;
            async16(gAb + (size_t)(m0 + row) * 1024 + gofs, ldst);
            ldst = (char*)sB + kc * 8192 + rowblk * 64 + lane * 16;
            async16(gBb + (size_t)(t0 + row) * 1024 + gofs, ldst);
        }
        __syncthreads();

        #pragma unroll
        for (int kc = 0; kc < 2; kc++) {
            short8 bv[4];
            #pragma unroll
            for (int ni = 0; ni < 4; ni++)
                bv[ni] = *(const short8*)((const char*)sB + kc * 8192
                        + (wn + ni * 16 + (lane & 15)) * 64 + (lane >> 4) * 16);
            #pragma unroll
            for (int mi = 0; mi < 4; mi++) {
                short8 av = *(const short8*)((const char*)sA + kc * 8192
                        + (wm + mi * 16 + (lane & 15)) * 64 + (lane >> 4) * 16);
                #pragma unroll
                for (int ni = 0; ni < 4; ni++)
                    acc[mi][ni] = __builtin_amdgcn_mfma_f32_16x16x32_bf16(
                        av, bv[ni], acc[mi][ni], 0, 0, 0);
            }
        }
    }

    // epilogue: C/D col=lane&15, row=(lane>>4)*4+r (dtype-independent)
    const int fr = lane & 15;
    const int rq = (lane >> 4) * 4;
    const float sp = dstd[p] + 1e-6f;
    #pragma unroll
    for (int mi = 0; mi < 4; mi++) {
        const int mb = m0 + wm + mi * 16 + rq;
        float rt[4];
        #pragma unroll
        for (int r = 0; r < 4; r++) rt[r] = rowterm[(mb + r) * 4 + p];
        #pragma unroll
        for (int ni = 0; ni < 4; ni++) {
            const int o = n0 + wn + ni * 16 + fr;
            const float bn = bias[o];
            float* cp = C + (size_t)mb * OUT_F + o;
            #pragma unroll
            for (int r = 0; r < 4; r++)
                cp[(size_t)r * OUT_F] = acc[mi][ni][r] * sp + rt[r] + bn;
        }
    }
}

extern "C" void kernel_launch(void* const* d_in, const int* in_sizes, int n_in,
                              void* d_out, int out_size, void* d_ws, size_t ws_size,
                              hipStream_t stream) {
    const float* x     = (const float*)d_in[0];   // (4,2048,4096)
    const float* vq    = (const float*)d_in[1];   // (16384,4,32)
    const float* wdec  = (const float*)d_in[2];   // (4,32,256)
    const float* bdec  = (const float*)d_in[3];   // (4,256)
    const float* dmean = (const float*)d_in[4];   // (4,1)
    const float* dstd  = (const float*)d_in[5];   // (4,1)
    const float* bias  = (const float*)d_in[6];   // (4096,)
    float* out = (float*)d_out;

    unsigned short* y   = (unsigned short*)d_ws;              // 33.55 MB
    unsigned short* vqh = y + (size_t)4 * M_DIM * 512;        //  4.19 MB
    float* rowterm = (float*)(vqh + (size_t)4 * 1024 * 512);  //  131 KB

    prep_tables<<<2048, 256, 0, stream>>>(vq, vqh);
    gen_y<<<M_DIM / 8, 256, 0, stream>>>(x, wdec, bdec, dmean, dstd, y, rowterm);
    gemm_y<<<dim3(M_DIM / 128, OUT_F / 128), 256, 0, stream>>>(
        y, vqh, rowterm, dstd, bias, out);
}

// Round 5
// 284.467 us; speedup vs baseline: 1.1689x; 1.1689x over previous
//
#include <hip/hip_runtime.h>
#include <stdint.h>

#define M_DIM 8192   // 4*2048 rows of x
#define IN_F  4096
#define OUT_F 4096
#define P_LAY 4

// Factorized algorithm (W is low-rank by construction):
//   W[o,i] = sp*(vq[t*16+i8, p, :]·wdec[p,:,c]) + sp*bdec[p,c] + dmean[p]
//     with p=o>>10, t=o&1023, i8=i>>8, c=i&255, sp=dstd[p]+1e-6
//   out[s,o] = sp * Sum_j y[s,p,j]*vqh[p,t,j] + rowterm[s,p] + bias[o]
//     y[s,p,i8,l] = Sum_c x[s,i8*256+c]*wdec[p,l,c]      (stage 1, 9.7 GFLOP)
//     j = l*16 + i8 (l-major; chosen so stage-1 epilogue stores coalesce)
//     rowterm[s,p] = sp*Sum_c xc[s,c]*bdec[p,c] + dmean[p]*xsum[s]
// 43 GFLOP total vs 275 GFLOP direct; no i8 quantization needed.
//
// Session accounting: ~160 us of every dur_us is two harness workspace-poison
// fills (536 MB @ ~80 us each) — fixed overhead, not ours.

typedef __attribute__((ext_vector_type(8))) short short8;   // 8 bf16 (4 VGPR)
typedef __attribute__((ext_vector_type(4))) float f32x4;

__device__ inline unsigned short f2bf(float f) {            // RNE f32->bf16
    unsigned int u = __builtin_bit_cast(unsigned int, f);
    u += 0x7fffu + ((u >> 16) & 1u);
    return (unsigned short)(u >> 16);
}

// ---------------- kernel 1: build bf16 tables (vqh, wdech) -----------------
// vqh[p][t][j= l*16+i8] = bf16(vq[(t*16+i8)*4*32 + p*32 + l])   (4 MB)
// wdech[n][c], n in [0,144): n<128 -> wdec flat copy (n=p*32+l);
//   n in [128,132) -> bdec[n-128][c]; n==132 -> 1.0 (xsum col); else 0.
__global__ __launch_bounds__(256)
void prep_tables(const float* __restrict__ vq, const float* __restrict__ wdec,
                 const float* __restrict__ bdec,
                 unsigned short* __restrict__ vqh,
                 unsigned short* __restrict__ wdech) {
    const int b = blockIdx.x;
    if (b < 2048) {
        const int o4  = (b * 256 + threadIdx.x) * 4;   // 4 consecutive j
        const int p   = o4 >> 19;
        const int t   = (o4 >> 9) & 1023;
        const int l   = (o4 >> 4) & 31;
        const int i80 = o4 & 15;
        ushort4 pk;
        pk.x = f2bf(vq[((size_t)(t * 16 + i80 + 0) * 4 + p) * 32 + l]);
        pk.y = f2bf(vq[((size_t)(t * 16 + i80 + 1) * 4 + p) * 32 + l]);
        pk.z = f2bf(vq[((size_t)(t * 16 + i80 + 2) * 4 + p) * 32 + l]);
        pk.w = f2bf(vq[((size_t)(t * 16 + i80 + 3) * 4 + p) * 32 + l]);
        *(ushort4*)(vqh + o4) = pk;
    } else {
        const int g4 = ((b - 2048) * 256 + threadIdx.x) * 4;  // [0, 36864)
        const int n  = g4 >> 8;
        const int c0 = g4 & 255;
        float v[4];
        #pragma unroll
        for (int jj = 0; jj < 4; jj++) {
            if      (n < 128)  v[jj] = wdec[g4 + jj];
            else if (n < 132)  v[jj] = bdec[(n - 128) * 256 + c0 + jj];
            else if (n == 132) v[jj] = 1.0f;
            else               v[jj] = 0.0f;
        }
        ushort4 pk;
        pk.x = f2bf(v[0]); pk.y = f2bf(v[1]); pk.z = f2bf(v[2]); pk.w = f2bf(v[3]);
        *(ushort4*)(wdech + g4) = pk;
    }
}

// ---------------- kernel 2: stage-1 GEMM, occupancy-tuned ------------------
// Round-4 post-mortem: c-split double-staging cost > occupancy gain (which
// never materialized: 25% = 8 waves/CU, LDS granularity). This version:
// round-2's SINGLE 64 KB staged table (rows 0..127 of wdech, XOR-swizzled,
// proven) + mi=2 s-rows/wave (VGPR ~84 <= 128 -> 4 waves/SIMD possible) +
// LB(256,4) + grid 1024 (4 blocks/CU avail; LDS admits 2 even at coarse
// granularity) -> target 16 waves/CU, 2x round-2's latency hiding.
// Depth-1 x prefetch: convert kc's regs to bf16, then reload the dead
// xu/xv registers with kc+1 before the MFMA burst (zero extra VGPRs).
__global__ __launch_bounds__(256, 4)
void gen_y(const float* __restrict__ x, const unsigned short* __restrict__ wdech,
           const float* __restrict__ dmean, const float* __restrict__ dstd,
           unsigned short* __restrict__ y,       // [4][8192][512] bf16
           float* __restrict__ rowterm) {        // [8192][4] f32
    __shared__ __attribute__((aligned(16))) unsigned short sW[32768]; // 64 KB

    const int tid  = threadIdx.x;
    const int lane = tid & 63;
    const int wave = tid >> 6;
    const int fr   = lane & 15;
    const int kg   = lane >> 4;
    const int bswz = (fr & 7) << 4;             // row&7 == fr&7 for row=nt*16+fr
    const int sb   = blockIdx.x * 8 + wave * 2; // 2 s-rows per wave

    // stage wdech rows 0..127 (bf16, 64 KB) -> LDS, swizzled (round-2 proven)
    #pragma unroll
    for (int it = 0; it < 16; ++it) {
        const int byte = (it * 256 + tid) * 16;
        const int n    = byte >> 9;
        const int swz  = byte ^ ((n & 7) << 4);
        *(int4*)((char*)sW + swz) = *(const int4*)((const char*)wdech + byte);
    }

    const float* xb0 = x + (size_t)sb * IN_F + fr * 256 + kg * 8;
    float4 xu[2], xv[2];
    #pragma unroll
    for (int mi = 0; mi < 2; ++mi) {
        xu[mi] = *(const float4*)(xb0 + (size_t)mi * IN_F);
        xv[mi] = *(const float4*)(xb0 + (size_t)mi * IN_F + 4);
    }
    __syncthreads();

    f32x4 acc[2][9] = {};
    #pragma unroll
    for (int kc = 0; kc < 8; ++kc) {
        // convert current kc (xu/xv die here)
        short8 a[2];
        #pragma unroll
        for (int mi = 0; mi < 2; ++mi) {
            short8 t;
            t[0] = (short)f2bf(xu[mi].x); t[1] = (short)f2bf(xu[mi].y);
            t[2] = (short)f2bf(xu[mi].z); t[3] = (short)f2bf(xu[mi].w);
            t[4] = (short)f2bf(xv[mi].x); t[5] = (short)f2bf(xv[mi].y);
            t[6] = (short)f2bf(xv[mi].z); t[7] = (short)f2bf(xv[mi].w);
            a[mi] = t;
        }
        // prefetch kc+1 into the freed regs; flies during the MFMA burst
        if (kc < 7) {
            #pragma unroll
            for (int mi = 0; mi < 2; ++mi) {
                xu[mi] = *(const float4*)(xb0 + (size_t)mi * IN_F + (kc + 1) * 32);
                xv[mi] = *(const float4*)(xb0 + (size_t)mi * IN_F + (kc + 1) * 32 + 4);
            }
        }
        #pragma unroll
        for (int nt = 0; nt < 9; ++nt) {
            short8 b;
            if (nt < 8)
                b = *(const short8*)((const char*)sW
                    + (((nt * 16 + fr) * 512 + kc * 64 + kg * 16) ^ bswz));
            else
                b = *(const short8*)(wdech + (size_t)(128 + fr) * 256 + kc * 32 + kg * 8);
            acc[0][nt] = __builtin_amdgcn_mfma_f32_16x16x32_bf16(a[0], b, acc[0][nt], 0, 0, 0);
            acc[1][nt] = __builtin_amdgcn_mfma_f32_16x16x32_bf16(a[1], b, acc[1][nt], 0, 0, 0);
        }
    }

    // y store: C/D col=lane&15, row(i8)=(lane>>4)*4+r. j = l*16+i8 with
    // l=(nt&1)*16+fr: offset = (nt&1)*256 + fr*16 + kg*4.
    #pragma unroll
    for (int mi = 0; mi < 2; ++mi) {
        const int s = sb + mi;
        #pragma unroll
        for (int nt = 0; nt < 8; ++nt) {
            ushort4 pk;
            pk.x = f2bf(acc[mi][nt][0]); pk.y = f2bf(acc[mi][nt][1]);
            pk.z = f2bf(acc[mi][nt][2]); pk.w = f2bf(acc[mi][nt][3]);
            const size_t off = ((size_t)((nt >> 1) * M_DIM + s) * 512)
                             + (nt & 1) * 256 + fr * 16 + kg * 4;
            *(ushort4*)(y + off) = pk;
        }
        // rowterm from nt=8 frag: cols 128+fr (fr<4 -> xb[p], fr==4 -> xsum)
        float cs = acc[mi][8][0] + acc[mi][8][1] + acc[mi][8][2] + acc[mi][8][3];
        cs += __shfl_xor(cs, 16);
        cs += __shfl_xor(cs, 32);
        const float xsum = __shfl(cs, 4);
        if (lane < 4)
            rowterm[s * 4 + lane] = (dstd[lane] + 1e-6f) * cs + dmean[lane] * xsum;
    }
}

// ---------------- kernel 3: stage-2 GEMM  out = sp*(Y_p @ V_p^T) + ... -----
__device__ inline void async16(const void* g, void* l) {
    __builtin_amdgcn_global_load_lds(
        (const __attribute__((address_space(1))) void*)g,
        (__attribute__((address_space(3))) void*)l, 16, 0, 0);
}

// Structure frozen (round-0-verified 128x128 / 4-wave / 2-barrier K-step).
// NEW: XCD-chunked p-locked block swizzle (index remap only). 1D grid 2048;
// lin%8 -> XCD; each XCD's 256-block chunk has CONSTANT p (V_p = 1 MB stays
// L2-resident) and n-fastest order (each 128 KB Y-panel reused by 8
// consecutive blocks; panels XCD-exclusive). Cuts ~1.3 GB L2/L3 re-reads
// toward the ~176 MB unique-traffic floor.
__global__ __launch_bounds__(256, 4)
void gemm_y(const unsigned short* __restrict__ Y,   // [4][8192][512] bf16
            const unsigned short* __restrict__ V,   // [4][1024][512] bf16
            const float* __restrict__ rowterm,      // [8192][4]
            const float* __restrict__ dstd,
            const float* __restrict__ bias,
            float* __restrict__ C) {
    __shared__ __attribute__((aligned(16))) unsigned short sA[2 * 128 * 32]; // 16 KB
    __shared__ __attribute__((aligned(16))) unsigned short sB[2 * 128 * 32];

    const int tid  = threadIdx.x;
    const int lane = tid & 63;
    const int wave = tid >> 6;
    const int wm = (wave >> 1) * 64;
    const int wn = (wave & 1) * 64;

    // bijective XCD swizzle: nwg=2048, chunk=256/XCD, p constant per XCD
    const int lin  = blockIdx.x;
    const int wg   = (lin & 7) * 256 + (lin >> 3);
    const int p    = wg >> 9;                       // [0,4)
    const int rest = wg & 511;
    const int m0   = (rest >> 3) * 128;             // m-panel, 8-block Y reuse
    const int t0   = (rest & 7) * 128;
    const int n0   = p * 1024 + t0;

    const char* gAb = (const char*)(Y + (size_t)p * M_DIM * 512);
    const char* gBb = (const char*)(V + (size_t)p * 1024  * 512);

    f32x4 acc[4][4] = {};
    for (int k0 = 0; k0 < 512; k0 += 64) {
        __syncthreads();
        #pragma unroll
        for (int q = 0; q < 4; q++) {
            const int u      = wave * 4 + q;
            const int kc     = u >> 3;
            const int rowblk = (u & 7) * 16;
            const int row    = rowblk + (lane >> 2);
            const int cb     = (lane & 3) * 16;
            const size_t gofs = (size_t)k0 * 2 + kc * 64 + cb;
            char* ldst = (char*)sA + kc * 8192 + rowblk * 64 + lane * 16;
            async16(gAb + (size_t)(m0 + row) * 1024 + gofs, ldst);
            ldst = (char*)sB + kc * 8192 + rowblk * 64 + lane * 16;
            async16(gBb + (size_t)(t0 + row) * 1024 + gofs, ldst);
        }
        __syncthreads();

        #pragma unroll
        for (int kc = 0; kc < 2; kc++) {
            short8 bv[4];
            #pragma unroll
            for (int ni = 0; ni < 4; ni++)
                bv[ni] = *(const short8*)((const char*)sB + kc * 8192
                        + (wn + ni * 16 + (lane & 15)) * 64 + (lane >> 4) * 16);
            #pragma unroll
            for (int mi = 0; mi < 4; mi++) {
                short8 av = *(const short8*)((const char*)sA + kc * 8192
                        + (wm + mi * 16 + (lane & 15)) * 64 + (lane >> 4) * 16);
                #pragma unroll
                for (int ni = 0; ni < 4; ni++)
                    acc[mi][ni] = __builtin_amdgcn_mfma_f32_16x16x32_bf16(
                        av, bv[ni], acc[mi][ni], 0, 0, 0);
            }
        }
    }

    // epilogue: C/D col=lane&15, row=(lane>>4)*4+r (dtype-independent)
    const int fr = lane & 15;
    const int rq = (lane >> 4) * 4;
    const float sp = dstd[p] + 1e-6f;
    #pragma unroll
    for (int mi = 0; mi < 4; mi++) {
        const int mb = m0 + wm + mi * 16 + rq;
        float rt[4];
        #pragma unroll
        for (int r = 0; r < 4; r++) rt[r] = rowterm[(mb + r) * 4 + p];
        #pragma unroll
        for (int ni = 0; ni < 4; ni++) {
            const int o = n0 + wn + ni * 16 + fr;
            const float bn = bias[o];
            float* cp = C + (size_t)mb * OUT_F + o;
            #pragma unroll
            for (int r = 0; r < 4; r++)
                cp[(size_t)r * OUT_F] = acc[mi][ni][r] * sp + rt[r] + bn;
        }
    }
}

extern "C" void kernel_launch(void* const* d_in, const int* in_sizes, int n_in,
                              void* d_out, int out_size, void* d_ws, size_t ws_size,
                              hipStream_t stream) {
    const float* x     = (const float*)d_in[0];   // (4,2048,4096)
    const float* vq    = (const float*)d_in[1];   // (16384,4,32)
    const float* wdec  = (const float*)d_in[2];   // (4,32,256)
    const float* bdec  = (const float*)d_in[3];   // (4,256)
    const float* dmean = (const float*)d_in[4];   // (4,1)
    const float* dstd  = (const float*)d_in[5];   // (4,1)
    const float* bias  = (const float*)d_in[6];   // (4096,)
    float* out = (float*)d_out;

    unsigned short* y     = (unsigned short*)d_ws;            // 33.55 MB
    unsigned short* vqh   = y + (size_t)4 * M_DIM * 512;      //  4.19 MB
    unsigned short* wdech = vqh + (size_t)4 * 1024 * 512;     //  73.7 KB
    float* rowterm = (float*)(wdech + 144 * 256);             //  131 KB

    prep_tables<<<2084, 256, 0, stream>>>(vq, wdec, bdec, vqh, wdech);
    gen_y<<<M_DIM / 8, 256, 0, stream>>>(x, wdech, dmean, dstd, y, rowterm);
    gemm_y<<<2048, 256, 0, stream>>>(y, vqh, rowterm, dstd, bias, out);
}

// Round 6
// 282.004 us; speedup vs baseline: 1.1791x; 1.0087x over previous
//
#include <hip/hip_runtime.h>
#include <stdint.h>

#define M_DIM 8192   // 4*2048 rows of x
#define IN_F  4096
#define OUT_F 4096
#define P_LAY 4

// Factorized algorithm (W is low-rank by construction):
//   W[o,i] = sp*(vq[t*16+i8, p, :]·wdec[p,:,c]) + sp*bdec[p,c] + dmean[p]
//     with p=o>>10, t=o&1023, i8=i>>8, c=i&255, sp=dstd[p]+1e-6
//   out[s,o] = sp * Sum_j y[s,p,j]*vqh[p,t,j] + rowterm[s,p] + bias[o]
//     y[s,p,i8,l] = Sum_c x[s,i8*256+c]*wdec[p,l,c]      (stage 1, 9.7 GFLOP)
//     j = l*16 + i8 (l-major; chosen so stage-1 epilogue stores coalesce)
//     rowterm[s,p] = sp*Sum_c xc[s,c]*bdec[p,c] + dmean[p]*xsum[s]
// 43 GFLOP total vs 275 GFLOP direct; no i8 quantization needed.
//
// Session accounting: ~160 us of every dur_us is two harness workspace-poison
// fills (536 MB @ ~80 us each) — fixed overhead, not ours. Round-5 ours ≈ 124 us.

typedef __attribute__((ext_vector_type(8))) short short8;   // 8 bf16 (4 VGPR)
typedef __attribute__((ext_vector_type(4))) float f32x4;

__device__ inline unsigned short f2bf(float f) {            // RNE f32->bf16
    unsigned int u = __builtin_bit_cast(unsigned int, f);
    u += 0x7fffu + ((u >> 16) & 1u);
    return (unsigned short)(u >> 16);
}

// ---------------- kernel 1: build bf16 tables (vqh, wdech) -----------------
// vqh[p][t][j= l*16+i8] = bf16(vq[(t*16+i8)*4*32 + p*32 + l])   (4 MB)
// wdech[n][c], n in [0,144): n<128 -> wdec flat copy (n=p*32+l);
//   n in [128,132) -> bdec[n-128][c]; n==132 -> 1.0 (xsum col); else 0.
__global__ __launch_bounds__(256)
void prep_tables(const float* __restrict__ vq, const float* __restrict__ wdec,
                 const float* __restrict__ bdec,
                 unsigned short* __restrict__ vqh,
                 unsigned short* __restrict__ wdech) {
    const int b = blockIdx.x;
    if (b < 2048) {
        const int o4  = (b * 256 + threadIdx.x) * 4;   // 4 consecutive j
        const int p   = o4 >> 19;
        const int t   = (o4 >> 9) & 1023;
        const int l   = (o4 >> 4) & 31;
        const int i80 = o4 & 15;
        ushort4 pk;
        pk.x = f2bf(vq[((size_t)(t * 16 + i80 + 0) * 4 + p) * 32 + l]);
        pk.y = f2bf(vq[((size_t)(t * 16 + i80 + 1) * 4 + p) * 32 + l]);
        pk.z = f2bf(vq[((size_t)(t * 16 + i80 + 2) * 4 + p) * 32 + l]);
        pk.w = f2bf(vq[((size_t)(t * 16 + i80 + 3) * 4 + p) * 32 + l]);
        *(ushort4*)(vqh + o4) = pk;
    } else {
        const int g4 = ((b - 2048) * 256 + threadIdx.x) * 4;  // [0, 36864)
        const int n  = g4 >> 8;
        const int c0 = g4 & 255;
        float v[4];
        #pragma unroll
        for (int jj = 0; jj < 4; jj++) {
            if      (n < 128)  v[jj] = wdec[g4 + jj];
            else if (n < 132)  v[jj] = bdec[(n - 128) * 256 + c0 + jj];
            else if (n == 132) v[jj] = 1.0f;
            else               v[jj] = 0.0f;
        }
        ushort4 pk;
        pk.x = f2bf(v[0]); pk.y = f2bf(v[1]); pk.z = f2bf(v[2]); pk.w = f2bf(v[3]);
        *(ushort4*)(wdech + g4) = pk;
    }
}

// ---------------- kernel 2: stage-1 GEMM, wave-dense -----------------------
// Round-5 post-mortem: 256-thr blocks + 64 KB LDS cap residency at
// 2 blocks/CU x 4 waves = 8 waves/CU — same as round 2; LB(256,4) couldn't
// raise it. THIS round: 512-thread blocks (8 waves) SHARE one 64 KB table
// -> 2 blocks/CU x 8 waves = 16 waves/CU (4/SIMD), 2x resident waves for
// the latency-bound x-stream. VGPR ~116 < 128 keeps 4/SIMD legal.
// Everything else (swizzle, depth-1 prefetch, MFMA loop, stores) unchanged.
__global__ __launch_bounds__(512, 4)
void gen_y(const float* __restrict__ x, const unsigned short* __restrict__ wdech,
           const float* __restrict__ dmean, const float* __restrict__ dstd,
           unsigned short* __restrict__ y,       // [4][8192][512] bf16
           float* __restrict__ rowterm) {        // [8192][4] f32
    __shared__ __attribute__((aligned(16))) unsigned short sW[32768]; // 64 KB

    const int tid  = threadIdx.x;
    const int lane = tid & 63;
    const int wave = tid >> 6;                   // 0..7
    const int fr   = lane & 15;
    const int kg   = lane >> 4;
    const int bswz = (fr & 7) << 4;              // row&7 == fr&7 for row=nt*16+fr
    const int sb   = blockIdx.x * 16 + wave * 2; // 2 s-rows per wave

    // stage wdech rows 0..127 (bf16, 64 KB) -> LDS, swizzled (round-2 proven)
    #pragma unroll
    for (int it = 0; it < 8; ++it) {
        const int byte = (it * 512 + tid) * 16;
        const int n    = byte >> 9;
        const int swz  = byte ^ ((n & 7) << 4);
        *(int4*)((char*)sW + swz) = *(const int4*)((const char*)wdech + byte);
    }

    const float* xb0 = x + (size_t)sb * IN_F + fr * 256 + kg * 8;
    float4 xu[2], xv[2];
    #pragma unroll
    for (int mi = 0; mi < 2; ++mi) {
        xu[mi] = *(const float4*)(xb0 + (size_t)mi * IN_F);
        xv[mi] = *(const float4*)(xb0 + (size_t)mi * IN_F + 4);
    }
    __syncthreads();

    f32x4 acc[2][9] = {};
    #pragma unroll
    for (int kc = 0; kc < 8; ++kc) {
        // convert current kc (xu/xv die here)
        short8 a[2];
        #pragma unroll
        for (int mi = 0; mi < 2; ++mi) {
            short8 t;
            t[0] = (short)f2bf(xu[mi].x); t[1] = (short)f2bf(xu[mi].y);
            t[2] = (short)f2bf(xu[mi].z); t[3] = (short)f2bf(xu[mi].w);
            t[4] = (short)f2bf(xv[mi].x); t[5] = (short)f2bf(xv[mi].y);
            t[6] = (short)f2bf(xv[mi].z); t[7] = (short)f2bf(xv[mi].w);
            a[mi] = t;
        }
        // prefetch kc+1 into the freed regs; flies during the MFMA burst
        if (kc < 7) {
            #pragma unroll
            for (int mi = 0; mi < 2; ++mi) {
                xu[mi] = *(const float4*)(xb0 + (size_t)mi * IN_F + (kc + 1) * 32);
                xv[mi] = *(const float4*)(xb0 + (size_t)mi * IN_F + (kc + 1) * 32 + 4);
            }
        }
        #pragma unroll
        for (int nt = 0; nt < 9; ++nt) {
            short8 b;
            if (nt < 8)
                b = *(const short8*)((const char*)sW
                    + (((nt * 16 + fr) * 512 + kc * 64 + kg * 16) ^ bswz));
            else
                b = *(const short8*)(wdech + (size_t)(128 + fr) * 256 + kc * 32 + kg * 8);
            acc[0][nt] = __builtin_amdgcn_mfma_f32_16x16x32_bf16(a[0], b, acc[0][nt], 0, 0, 0);
            acc[1][nt] = __builtin_amdgcn_mfma_f32_16x16x32_bf16(a[1], b, acc[1][nt], 0, 0, 0);
        }
    }

    // y store: C/D col=lane&15, row(i8)=(lane>>4)*4+r. j = l*16+i8 with
    // l=(nt&1)*16+fr: offset = (nt&1)*256 + fr*16 + kg*4.
    #pragma unroll
    for (int mi = 0; mi < 2; ++mi) {
        const int s = sb + mi;
        #pragma unroll
        for (int nt = 0; nt < 8; ++nt) {
            ushort4 pk;
            pk.x = f2bf(acc[mi][nt][0]); pk.y = f2bf(acc[mi][nt][1]);
            pk.z = f2bf(acc[mi][nt][2]); pk.w = f2bf(acc[mi][nt][3]);
            const size_t off = ((size_t)((nt >> 1) * M_DIM + s) * 512)
                             + (nt & 1) * 256 + fr * 16 + kg * 4;
            *(ushort4*)(y + off) = pk;
        }
        // rowterm from nt=8 frag: cols 128+fr (fr<4 -> xb[p], fr==4 -> xsum)
        float cs = acc[mi][8][0] + acc[mi][8][1] + acc[mi][8][2] + acc[mi][8][3];
        cs += __shfl_xor(cs, 16);
        cs += __shfl_xor(cs, 32);
        const float xsum = __shfl(cs, 4);
        if (lane < 4)
            rowterm[s * 4 + lane] = (dstd[lane] + 1e-6f) * cs + dmean[lane] * xsum;
    }
}

// ---------------- kernel 3: stage-2 GEMM  out = sp*(Y_p @ V_p^T) + ... -----
__device__ inline void async16(const void* g, void* l) {
    __builtin_amdgcn_global_load_lds(
        (const __attribute__((address_space(1))) void*)g,
        (__attribute__((address_space(3))) void*)l, 16, 0, 0);
}

// Structure frozen (round-0-verified 128x128 / 4-wave / 2-barrier K-step +
// round-5 XCD-chunked p-locked swizzle). Unchanged this round (attribution).
__global__ __launch_bounds__(256, 4)
void gemm_y(const unsigned short* __restrict__ Y,   // [4][8192][512] bf16
            const unsigned short* __restrict__ V,   // [4][1024][512] bf16
            const float* __restrict__ rowterm,      // [8192][4]
            const float* __restrict__ dstd,
            const float* __restrict__ bias,
            float* __restrict__ C) {
    __shared__ __attribute__((aligned(16))) unsigned short sA[2 * 128 * 32]; // 16 KB
    __shared__ __attribute__((aligned(16))) unsigned short sB[2 * 128 * 32];

    const int tid  = threadIdx.x;
    const int lane = tid & 63;
    const int wave = tid >> 6;
    const int wm = (wave >> 1) * 64;
    const int wn = (wave & 1) * 64;

    // bijective XCD swizzle: nwg=2048, chunk=256/XCD, p constant per XCD
    const int lin  = blockIdx.x;
    const int wg   = (lin & 7) * 256 + (lin >> 3);
    const int p    = wg >> 9;                       // [0,4)
    const int rest = wg & 511;
    const int m0   = (rest >> 3) * 128;             // m-panel, 8-block Y reuse
    const int t0   = (rest & 7) * 128;
    const int n0   = p * 1024 + t0;

    const char* gAb = (const char*)(Y + (size_t)p * M_DIM * 512);
    const char* gBb = (const char*)(V + (size_t)p * 1024  * 512);

    f32x4 acc[4][4] = {};
    for (int k0 = 0; k0 < 512; k0 += 64) {
        __syncthreads();
        #pragma unroll
        for (int q = 0; q < 4; q++) {
            const int u      = wave * 4 + q;
            const int kc     = u >> 3;
            const int rowblk = (u & 7) * 16;
            const int row    = rowblk + (lane >> 2);
            const int cb     = (lane & 3) * 16;
            const size_t gofs = (size_t)k0 * 2 + kc * 64 + cb;
            char* ldst = (char*)sA + kc * 8192 + rowblk * 64 + lane * 16;
            async16(gAb + (size_t)(m0 + row) * 1024 + gofs, ldst);
            ldst = (char*)sB + kc * 8192 + rowblk * 64 + lane * 16;
            async16(gBb + (size_t)(t0 + row) * 1024 + gofs, ldst);
        }
        __syncthreads();

        #pragma unroll
        for (int kc = 0; kc < 2; kc++) {
            short8 bv[4];
            #pragma unroll
            for (int ni = 0; ni < 4; ni++)
                bv[ni] = *(const short8*)((const char*)sB + kc * 8192
                        + (wn + ni * 16 + (lane & 15)) * 64 + (lane >> 4) * 16);
            #pragma unroll
            for (int mi = 0; mi < 4; mi++) {
                short8 av = *(const short8*)((const char*)sA + kc * 8192
                        + (wm + mi * 16 + (lane & 15)) * 64 + (lane >> 4) * 16);
                #pragma unroll
                for (int ni = 0; ni < 4; ni++)
                    acc[mi][ni] = __builtin_amdgcn_mfma_f32_16x16x32_bf16(
                        av, bv[ni], acc[mi][ni], 0, 0, 0);
            }
        }
    }

    // epilogue: C/D col=lane&15, row=(lane>>4)*4+r (dtype-independent)
    const int fr = lane & 15;
    const int rq = (lane >> 4) * 4;
    const float sp = dstd[p] + 1e-6f;
    #pragma unroll
    for (int mi = 0; mi < 4; mi++) {
        const int mb = m0 + wm + mi * 16 + rq;
        float rt[4];
        #pragma unroll
        for (int r = 0; r < 4; r++) rt[r] = rowterm[(mb + r) * 4 + p];
        #pragma unroll
        for (int ni = 0; ni < 4; ni++) {
            const int o = n0 + wn + ni * 16 + fr;
            const float bn = bias[o];
            float* cp = C + (size_t)mb * OUT_F + o;
            #pragma unroll
            for (int r = 0; r < 4; r++)
                cp[(size_t)r * OUT_F] = acc[mi][ni][r] * sp + rt[r] + bn;
        }
    }
}

extern "C" void kernel_launch(void* const* d_in, const int* in_sizes, int n_in,
                              void* d_out, int out_size, void* d_ws, size_t ws_size,
                              hipStream_t stream) {
    const float* x     = (const float*)d_in[0];   // (4,2048,4096)
    const float* vq    = (const float*)d_in[1];   // (16384,4,32)
    const float* wdec  = (const float*)d_in[2];   // (4,32,256)
    const float* bdec  = (const float*)d_in[3];   // (4,256)
    const float* dmean = (const float*)d_in[4];   // (4,1)
    const float* dstd  = (const float*)d_in[5];   // (4,1)
    const float* bias  = (const float*)d_in[6];   // (4096,)
    float* out = (float*)d_out;

    unsigned short* y     = (unsigned short*)d_ws;            // 33.55 MB
    unsigned short* vqh   = y + (size_t)4 * M_DIM * 512;      //  4.19 MB
    unsigned short* wdech = vqh + (size_t)4 * 1024 * 512;     //  73.7 KB
    float* rowterm = (float*)(wdech + 144 * 256);             //  131 KB

    prep_tables<<<2084, 256, 0, stream>>>(vq, wdec, bdec, vqh, wdech);
    gen_y<<<M_DIM / 16, 512, 0, stream>>>(x, wdech, dmean, dstd, y, rowterm);
    gemm_y<<<2048, 256, 0, stream>>>(y, vqh, rowterm, dstd, bias, out);
}